// Round 7
// baseline (122.100 us; speedup 1.0000x reference)
//
#include <hip/hip_runtime.h>

#define WPB 4                // waves (rays) per block
#define BLOCK (64 * WPB)
#define SC 256               // coarse samples per ray
#define SF 128               // fine (importance) samples per ray

typedef float v2f __attribute__((ext_vector_type(2)));
typedef float v4f __attribute__((ext_vector_type(4)));

__device__ __forceinline__ float fexp2(float x) {
#if __has_builtin(__builtin_amdgcn_exp2f)
    return __builtin_amdgcn_exp2f(x);
#else
    return exp2f(x);
#endif
}
__device__ __forceinline__ float frcp(float x) {
#if __has_builtin(__builtin_amdgcn_rcpf)
    return __builtin_amdgcn_rcpf(x);
#else
    return 1.0f / x;
#endif
}
__device__ __forceinline__ float frsq(float x) {
#if __has_builtin(__builtin_amdgcn_rsqf)
    return __builtin_amdgcn_rsqf(x);
#else
    return rsqrtf(x);
#endif
}

// DPP move. bc=false: invalid/masked lanes read `oldv`.
// bc=true: invalid source lanes read 0 (masked rows still return oldv).
#define DPPF(oldv, x, ctrl, rmask, bc)                                          \
    __int_as_float(__builtin_amdgcn_update_dpp(                                 \
        __float_as_int(oldv), __float_as_int(x), (ctrl), (rmask), 0xf, (bc)))

// gfx9 DPP ctrl codes
#define ROW_SHR1   0x111
#define ROW_SHR2   0x112
#define ROW_SHR4   0x114
#define ROW_SHR8   0x118
#define WAVE_SHL1  0x130   // lane i <- lane i+1 (lane63 -> old)
#define WAVE_SHR1  0x138   // lane i <- lane i-1 (lane0  -> old)
#define ROW_BC15   0x142
#define ROW_BC31   0x143

__device__ __forceinline__ float scan_mul_incl(float x) {
    x *= DPPF(1.0f, x, ROW_SHR1, 0xf, false);
    x *= DPPF(1.0f, x, ROW_SHR2, 0xf, false);
    x *= DPPF(1.0f, x, ROW_SHR4, 0xf, false);
    x *= DPPF(1.0f, x, ROW_SHR8, 0xf, false);
    x *= DPPF(1.0f, x, ROW_BC15, 0xa, false);   // rows 1,3 only
    x *= DPPF(1.0f, x, ROW_BC31, 0xc, false);   // rows 2,3 only
    return x;                      // inclusive product; lane63 = total
}
// bound_ctrl=true: invalid lanes contribute 0 (add identity); masked rows get
// old=0 so x+0=x. Fusable into v_add_f32_dpp.
__device__ __forceinline__ float scan_add_incl(float x) {
    x += DPPF(0.0f, x, ROW_SHR1, 0xf, true);
    x += DPPF(0.0f, x, ROW_SHR2, 0xf, true);
    x += DPPF(0.0f, x, ROW_SHR4, 0xf, true);
    x += DPPF(0.0f, x, ROW_SHR8, 0xf, true);
    x += DPPF(0.0f, x, ROW_BC15, 0xa, true);    // rows 1,3 only
    x += DPPF(0.0f, x, ROW_BC31, 0xc, true);    // rows 2,3 only
    return x;                      // inclusive sum; lane63 = total
}
__device__ __forceinline__ float readlanef(float x, int l) {
    return __int_as_float(__builtin_amdgcn_readlane(__float_as_int(x), l));
}

__global__ __launch_bounds__(BLOCK) void nerf_render(
    const float* __restrict__ rays_o, const float* __restrict__ rays_d,
    const float* __restrict__ bgp, float* __restrict__ out, int N) {
    const int wid  = __builtin_amdgcn_readfirstlane(threadIdx.x >> 6);  // wave-uniform -> SGPR
    const int lane = threadIdx.x & 63;
    const int ray  = __builtin_amdgcn_readfirstlane(blockIdx.x * WPB + wid);
    __shared__ float cdf_s[WPB][SC];   // wave-private rows; no block barrier needed

    const float L2_10 = 3.3219280948873623f;   // log2(10)
    const float L2_E  = 1.4426950408889634f;   // log2(e)
    const float DLT   = 0.0078125f;            // 1/128
    const float C2  = -4.0f * L2_E;            // exp(-4*ssq)        = 2^(C2*ssq)
    const float C1  = -L2_E * 25.0f * DLT;     // exp(-25*e^..*DLT)  = 2^(C1*sg)
    const float C25 = -L2_E * 25.0f;           // fine: 2^(C25*sg*del)
    const float CADD = 1e-4f / 256.0f;

    float ox = rays_o[ray * 3 + 0], oy = rays_o[ray * 3 + 1], oz = rays_o[ray * 3 + 2];
    float dx = rays_d[ray * 3 + 0], dy = rays_d[ray * 3 + 1], dz = rays_d[ray * 3 + 2];
    {   // normalize direction
        float rn = frsq(dx * dx + dy * dy + dz * dz);
        dx *= rn; dy *= rn; dz *= rn;
    }
    // sigmoid direction-bias, pre-scaled for a single pk_fma per channel
    float dxn = dx * (-0.1f * L2_E), dyn = dy * (-0.1f * L2_E), dzn = dz * (-0.1f * L2_E);

    // ---------------- coarse pass: lane owns k = 4*lane .. 4*lane+3 ----------------
    // (this whole section is BIT-FROZEN: CDF bits decide searchsorted boundaries)
    float zl0 = -1.0f + (float)(lane << 2) * DLT;
    float z0  = fexp2(zl0 * L2_10);
    v2f zz[2];
    zz[0].x = z0;                          zz[0].y = z0 * 1.0181517217011025f;  // 10^(1/128)
    zz[1].x = z0 * 1.0366329284377645f;    zz[1].y = z0 * 1.0554494416179205f;  // 10^(2/128),10^(3/128)

    v2f ee[2];
#pragma unroll
    for (int p = 0; p < 2; p++) {
        v2f z  = zz[p];
        v2f px = dx * z + ox, py = dy * z + oy, pz = dz * z + oz;   // pk_fma
        v2f nsq = px * px + py * py + pz * pz;                      // pk
        v2f rn; rn.x = frsq(nsq.x); rn.y = frsq(nsq.y);
        v2f t2 = 2.0f - rn;
        v2f fs = t2 * t2;
        v2f ssq;
        ssq.x = nsq.x > 1.0f ? fs.x : nsq.x;
        ssq.y = nsq.y > 1.0f ? fs.y : nsq.y;
        v2f sr = C2 * ssq;
        v2f sg; sg.x = fexp2(sr.x); sg.y = fexp2(sr.y);             // exp(-4*ssq)
        v2f ea = C1 * sg;
        ee[p].x = fexp2(ea.x); ee[p].y = fexp2(ea.y);               // exp(-sig*DLT)
    }
    if (lane == 63) ee[1].y = 1.0f;        // last delta = 0 -> alpha 0

    // transmittance: exclusive product scan across lanes
    float lp  = (ee[0].x * ee[0].y) * (ee[1].x * ee[1].y);
    float tp  = scan_mul_incl(lp);
    float tin = DPPF(1.0f, tp, WAVE_SHR1, 0xf, false);

    v2f om0 = 1.0f - ee[0], om1 = 1.0f - ee[1];
    float c1 = ee[0].x, c2 = c1 * ee[0].y, c3 = c2 * ee[1].x;
    v2f t01; t01.x = tin;      t01.y = tin * c1;
    v2f t23; t23.x = tin * c2; t23.y = tin * c3;
    v2f w01 = om0 * t01, w23 = om1 * t23;

    // reweight (scale 0.5 uniform -> cancels in normalization)
    float wprev = DPPF(0.0f, w23.y, WAVE_SHR1, 0xf, false);  // lane-1's w3; lane0 -> 0
    float wnext = DPPF(0.0f, w01.x, WAVE_SHL1, 0xf, false);  // lane+1's w0; lane63 -> 0
    float m0 = fmaxf(wprev, w01.x), m1 = fmaxf(w01.x, w01.y),
          m2 = fmaxf(w01.y, w23.x), m3 = fmaxf(w23.x, w23.y),
          m4 = fmaxf(w23.y, wnext);
    float wr0 = 0.5f * (m0 + m1) + CADD, wr1 = 0.5f * (m1 + m2) + CADD,
          wr2 = 0.5f * (m2 + m3) + CADD, wr3 = 0.5f * (m3 + m4) + CADD;

    // CDF: lane-local inclusive sums + wave add-scan
    float s0 = wr0, s1 = s0 + wr1, s2 = s1 + wr2, s3 = s2 + wr3;
    float incl = scan_add_incl(s3);
    float exb  = DPPF(0.0f, incl, WAVE_SHR1, 0xf, true);
    float invT = frcp(readlanef(incl, 63));
    v2f cdfa; cdfa.x = (exb + s0) * invT; cdfa.y = (exb + s1) * invT;
    v2f cdfb; cdfb.x = (exb + s2) * invT; cdfb.y = (exb + s3) * invT;
    *(v2f*)&cdf_s[wid][(lane << 2) + 0] = cdfa;
    *(v2f*)&cdf_s[wid][(lane << 2) + 2] = cdfb;
    const float* cdf = cdf_s[wid];
    // no __syncthreads(): LDS row is wave-private; compiler orders via lgkmcnt

    // All level-1/level-2 pivots have index 16m-1 = 4*(4m-1)+3 -> lane(4m-1).cdfb.y.
    // Broadcast the 15 of them once (wave-uniform); bit-identical to the LDS copy.
    const float P1  = readlanef(cdfb.y, 3),  P2  = readlanef(cdfb.y, 7),  P3  = readlanef(cdfb.y, 11);
    const float P4  = readlanef(cdfb.y, 15), P5  = readlanef(cdfb.y, 19), P6  = readlanef(cdfb.y, 23);
    const float P7  = readlanef(cdfb.y, 27), P8  = readlanef(cdfb.y, 31), P9  = readlanef(cdfb.y, 35);
    const float P10 = readlanef(cdfb.y, 39), P11 = readlanef(cdfb.y, 43), P12 = readlanef(cdfb.y, 47);
    const float P13 = readlanef(cdfb.y, 51), P14 = readlanef(cdfb.y, 55), P15 = readlanef(cdfb.y, 59);

    // -------- inverse-CDF sampling: 2 register levels + 1 LDS level + final b128 --------
    // Invariant at each level: answer inds in [base, base+S) and cdf[base+S-1] > u.
    // Bin selection bit-identical to np.searchsorted(cdf, u, 'right').
    float zlf[2], zvs[2];
    // u = (2*lane + jj + 0.5) * 2^-7, exact; same value as (j+0.5)/128
    float ubase = (float)lane * 0.015625f;
#pragma unroll
    for (int jj = 0; jj < 2; jj++) {
        float u = ubase + (jj ? 0.01171875f : 0.00390625f);   // (jj+0.5)*2^-7
        // level 1 (stride 64): a >= b >= c by monotonicity
        bool a = (P4 <= u), b = (P8 <= u), c = (P12 <= u);
        int q1 = (int)a + (int)b + (int)c;
        // level 2 (stride 16): probes selected from broadcast registers
        float qa = c ? P13 : (b ? P9  : (a ? P5 : P1));
        float qb = c ? P14 : (b ? P10 : (a ? P6 : P2));
        float qc = c ? P15 : (b ? P11 : (a ? P7 : P3));
        int base = (q1 << 6) + ((((int)(qa <= u) + (int)(qb <= u) + (int)(qc <= u))) << 4);
        {   // level 3 (stride 4): LDS, imm offsets off one address
            float ra_ = cdf[base + 3], rb_ = cdf[base + 7], rc_ = cdf[base + 11];
            base += (((int)(ra_ <= u) + (int)(rb_ <= u) + (int)(rc_ <= u)) << 2);
        }
        v4f r = *(const v4f*)(cdf + base);          // ds_read_b128, 16B-aligned
        int bm1 = base - 1; if (bm1 < 0) bm1 = 0;
        float cm1 = cdf[bm1];                        // cdf[max(base-1,0)] == np's fallback
        bool le0 = (r.x <= u), le1 = (r.y <= u), le2 = (r.z <= u);  // r.w > u by invariant
        int cnt  = (int)le0 + (int)le1 + (int)le2;
        int inds = base + cnt;
        float c1v = le2 ? r.w : (le1 ? r.z : (le0 ? r.y : r.x));    // cdf[inds]
        float c0  = le2 ? r.z : (le1 ? r.y : (le0 ? r.x : cm1));    // cdf[max(inds-1,0)]
        float dnm = c1v - c0;
        dnm = (dnm < 1e-8f) ? 1.0f : dnm;
        float t = (u - c0) * frcp(dnm);
        t = t < 0.0f ? 0.0f : (t > 1.0f ? 1.0f : t);
        // inds>=1: b0=-1+(inds-1)*DLT, b1-b0=DLT exactly; inds==0: zlf=-1
        float f = (inds == 0) ? 0.0f : ((float)(inds - 1) + t);
        zlf[jj] = fmaf(DLT, f, -1.0f);
        zvs[jj] = f * 0.00390625f;   // (zlf+1)/2 to <=1ulp: exact 2^-8 * f
    }

    // ---------------- fine render (one packed pair per lane) ----------------
    float zlf2 = DPPF(zlf[1], zlf[0], WAVE_SHL1, 0xf, false);  // zlf[2*lane+2]; lane63 -> own zlf[1] => del.y = 0
    v2f del; del.x = zlf[1] - zlf[0]; del.y = zlf2 - zlf[1];
    v2f zf;  zf.x = fexp2(zlf[0] * L2_10); zf.y = fexp2(zlf[1] * L2_10);
    v2f invz; invz.x = frcp(zf.x); invz.y = frcp(zf.y);
    v2f px = dx * zf + ox, py = dy * zf + oy, pz = dz * zf + oz;
    v2f nsq = px * px + py * py + pz * pz;
    v2f rn; rn.x = frsq(nsq.x); rn.y = frsq(nsq.y);
    v2f t2 = 2.0f - rn;
    v2f fs = t2 * t2;
    v2f fc = rn * t2;
    v2f ssq, fac;
    ssq.x = nsq.x > 1.0f ? fs.x : nsq.x;  fac.x = nsq.x > 1.0f ? fc.x : 1.0f;
    ssq.y = nsq.y > 1.0f ? fs.y : nsq.y;  fac.y = nsq.y > 1.0f ? fc.y : 1.0f;
    v2f sr = C2 * ssq;
    v2f sg; sg.x = fexp2(sr.x); sg.y = fexp2(sr.y);        // exp(-4*ssq)
    v2f ea = (C25 * sg) * del;                             // log2(ef)  (lane63: ea.y = 0 exactly)
    v2f ef; ef.x = fexp2(ea.x); ef.y = fexp2(ea.y);        // exp(-sig*del)

    v2f sx = px * fac, sy = py * fac, sz = pz * fac;       // contracted point
    v2f axr = sx * (-L2_E) + dxn;                          // pk_mul + pk_fma per channel
    v2f axg = sy * (-L2_E) + dyn;
    v2f axb = sz * (-L2_E) + dzn;
    v2f er; er.x = fexp2(axr.x); er.y = fexp2(axr.y);
    v2f eg; eg.x = fexp2(axg.x); eg.y = fexp2(axg.y);
    v2f eb; eb.x = fexp2(axb.x); eb.y = fexp2(axb.y);
    v2f dr = 1.0f + er, dg = 1.0f + eg, db = 1.0f + eb;
    v2f rv; rv.x = frcp(dr.x); rv.y = frcp(dr.y);
    v2f gv; gv.x = frcp(dg.x); gv.y = frcp(dg.y);
    v2f bv; bv.x = frcp(db.x); bv.y = frcp(db.y);

    // log-domain transmittance: fused add-scan on log2(ef) + one exp2
    float asum = ea.x + ea.y;
    float tincl = scan_add_incl(asum);                       // inclusive log-sum
    float texc  = DPPF(0.0f, tincl, WAVE_SHR1, 0xf, true);   // exclusive; lane0 -> 0
    float tinf  = fexp2(texc);                               // incoming transmittance
    float Ttot  = fexp2(readlanef(tincl, 63));               // total transmittance = 1 - sum(wf)
    float wf0 = (1.0f - ef.x) * tinf;
    float wf1 = (1.0f - ef.y) * (tinf * ef.x);
    v2f wfv; wfv.x = wf0; wfv.y = wf1;

    v2f pr = wfv * rv, pg = wfv * gv, pb = wfv * bv, pi = wfv * invz;
    float ar = scan_add_incl(pr.x + pr.y);    // lane63 = total
    float ag = scan_add_incl(pg.x + pg.y);
    float ab = scan_add_incl(pb.x + pb.y);
    float ai = scan_add_incl(pi.x + pi.y);

    // ---------------- outputs: [image N*3][wf N*128][zvs N*128][invdepth N] ----------------
    // 32-bit offsets: total elements 65536*260 < 2^25
    const unsigned NN = (unsigned)N;
    float* wf_base  = out + 3u * NN;
    float* zvs_base = wf_base + NN * (unsigned)SF;
    float* inv_base = zvs_base + NN * (unsigned)SF;
    unsigned col = (unsigned)ray * (unsigned)SF + (unsigned)(lane << 1);
    *(float2*)(wf_base + col) = make_float2(wf0, wf1);
    *(float2*)(zvs_base + col) = make_float2(zvs[0], zvs[1]);
    if (lane == 63) {
        out[(unsigned)ray * 3u + 0u] = fmaf(Ttot, bgp[0], ar);
        out[(unsigned)ray * 3u + 1u] = fmaf(Ttot, bgp[1], ag);
        out[(unsigned)ray * 3u + 2u] = fmaf(Ttot, bgp[2], ab);
        inv_base[(unsigned)ray] = ai;
    }
}

extern "C" void kernel_launch(void* const* d_in, const int* in_sizes, int n_in,
                              void* d_out, int out_size, void* d_ws, size_t ws_size,
                              hipStream_t stream) {
    const float* rays_o = (const float*)d_in[0];
    const float* rays_d = (const float*)d_in[1];
    const float* bg     = (const float*)d_in[2];
    float* out = (float*)d_out;
    int N = in_sizes[0] / 3;
    int blocks = (N + WPB - 1) / WPB;
    nerf_render<<<blocks, BLOCK, 0, stream>>>(rays_o, rays_d, bg, out, N);
}

// Round 8
// 115.999 us; speedup vs baseline: 1.0526x; 1.0526x over previous
//
#include <hip/hip_runtime.h>

#define WPB 4                // waves (rays) per block
#define BLOCK (64 * WPB)
#define SC 256               // coarse samples per ray
#define SF 128               // fine (importance) samples per ray

typedef float v2f __attribute__((ext_vector_type(2)));
typedef float v4f __attribute__((ext_vector_type(4)));

__device__ __forceinline__ float fexp2(float x) {
#if __has_builtin(__builtin_amdgcn_exp2f)
    return __builtin_amdgcn_exp2f(x);
#else
    return exp2f(x);
#endif
}
__device__ __forceinline__ float frcp(float x) {
#if __has_builtin(__builtin_amdgcn_rcpf)
    return __builtin_amdgcn_rcpf(x);
#else
    return 1.0f / x;
#endif
}
__device__ __forceinline__ float frsq(float x) {
#if __has_builtin(__builtin_amdgcn_rsqf)
    return __builtin_amdgcn_rsqf(x);
#else
    return rsqrtf(x);
#endif
}

// DPP move. bc=false: invalid/masked lanes read `oldv`.
// bc=true: invalid source lanes read 0 (masked rows still return oldv).
#define DPPF(oldv, x, ctrl, rmask, bc)                                          \
    __int_as_float(__builtin_amdgcn_update_dpp(                                 \
        __float_as_int(oldv), __float_as_int(x), (ctrl), (rmask), 0xf, (bc)))

// gfx9 DPP ctrl codes
#define ROW_SHR1   0x111
#define ROW_SHR2   0x112
#define ROW_SHR4   0x114
#define ROW_SHR8   0x118
#define WAVE_SHL1  0x130   // lane i <- lane i+1 (lane63 -> old)
#define WAVE_SHR1  0x138   // lane i <- lane i-1 (lane0  -> old)
#define ROW_BC15   0x142
#define ROW_BC31   0x143

__device__ __forceinline__ float scan_mul_incl(float x) {
    x *= DPPF(1.0f, x, ROW_SHR1, 0xf, false);
    x *= DPPF(1.0f, x, ROW_SHR2, 0xf, false);
    x *= DPPF(1.0f, x, ROW_SHR4, 0xf, false);
    x *= DPPF(1.0f, x, ROW_SHR8, 0xf, false);
    x *= DPPF(1.0f, x, ROW_BC15, 0xa, false);   // rows 1,3 only
    x *= DPPF(1.0f, x, ROW_BC31, 0xc, false);   // rows 2,3 only
    return x;                      // inclusive product; lane63 = total
}
// bound_ctrl=true: invalid lanes contribute 0 (add identity); masked rows get
// old=0 so x+0=x. Fusable into v_add_f32_dpp.
__device__ __forceinline__ float scan_add_incl(float x) {
    x += DPPF(0.0f, x, ROW_SHR1, 0xf, true);
    x += DPPF(0.0f, x, ROW_SHR2, 0xf, true);
    x += DPPF(0.0f, x, ROW_SHR4, 0xf, true);
    x += DPPF(0.0f, x, ROW_SHR8, 0xf, true);
    x += DPPF(0.0f, x, ROW_BC15, 0xa, true);    // rows 1,3 only
    x += DPPF(0.0f, x, ROW_BC31, 0xc, true);    // rows 2,3 only
    return x;                      // inclusive sum; lane63 = total
}
__device__ __forceinline__ float readlanef(float x, int l) {
    return __int_as_float(__builtin_amdgcn_readlane(__float_as_int(x), l));
}

__global__ __launch_bounds__(BLOCK) void nerf_render(
    const float* __restrict__ rays_o, const float* __restrict__ rays_d,
    const float* __restrict__ bgp, float* __restrict__ out, int N) {
    const int wid  = __builtin_amdgcn_readfirstlane(threadIdx.x >> 6);  // wave-uniform -> SGPR
    const int lane = threadIdx.x & 63;
    const int ray  = __builtin_amdgcn_readfirstlane(blockIdx.x * WPB + wid);
    __shared__ float cdf_s[WPB][SC];   // wave-private rows; no block barrier needed

    const float L2_10 = 3.3219280948873623f;   // log2(10)
    const float L2_E  = 1.4426950408889634f;   // log2(e)
    const float DLT   = 0.0078125f;            // 1/128
    const float C2  = -4.0f * L2_E;            // exp(-4*ssq)        = 2^(C2*ssq)
    const float C1  = -L2_E * 25.0f * DLT;     // exp(-25*e^..*DLT)  = 2^(C1*sg)
    const float C25 = -L2_E * 25.0f;           // fine: 2^(C25*sg*del)
    const float CADD = 1e-4f / 256.0f;

    float ox = rays_o[ray * 3 + 0], oy = rays_o[ray * 3 + 1], oz = rays_o[ray * 3 + 2];
    float dx = rays_d[ray * 3 + 0], dy = rays_d[ray * 3 + 1], dz = rays_d[ray * 3 + 2];
    {   // normalize direction
        float rn = frsq(dx * dx + dy * dy + dz * dz);
        dx *= rn; dy *= rn; dz *= rn;
    }
    // sigmoid direction-bias, pre-scaled for a single pk_fma per channel
    float dxn = dx * (-0.1f * L2_E), dyn = dy * (-0.1f * L2_E), dzn = dz * (-0.1f * L2_E);

    // ---------------- coarse pass: lane owns k = 4*lane .. 4*lane+3 ----------------
    // (this whole section is BIT-FROZEN: CDF bits decide searchsorted boundaries)
    float zl0 = -1.0f + (float)(lane << 2) * DLT;
    float z0  = fexp2(zl0 * L2_10);
    v2f zz[2];
    zz[0].x = z0;                          zz[0].y = z0 * 1.0181517217011025f;  // 10^(1/128)
    zz[1].x = z0 * 1.0366329284377645f;    zz[1].y = z0 * 1.0554494416179205f;  // 10^(2/128),10^(3/128)

    v2f ee[2];
#pragma unroll
    for (int p = 0; p < 2; p++) {
        v2f z  = zz[p];
        v2f px = dx * z + ox, py = dy * z + oy, pz = dz * z + oz;   // pk_fma
        v2f nsq = px * px + py * py + pz * pz;                      // pk
        v2f rn; rn.x = frsq(nsq.x); rn.y = frsq(nsq.y);
        v2f t2 = 2.0f - rn;
        v2f fs = t2 * t2;
        v2f ssq;
        ssq.x = nsq.x > 1.0f ? fs.x : nsq.x;
        ssq.y = nsq.y > 1.0f ? fs.y : nsq.y;
        v2f sr = C2 * ssq;
        v2f sg; sg.x = fexp2(sr.x); sg.y = fexp2(sr.y);             // exp(-4*ssq)
        v2f ea = C1 * sg;
        ee[p].x = fexp2(ea.x); ee[p].y = fexp2(ea.y);               // exp(-sig*DLT)
    }
    if (lane == 63) ee[1].y = 1.0f;        // last delta = 0 -> alpha 0

    // transmittance: exclusive product scan across lanes
    float lp  = (ee[0].x * ee[0].y) * (ee[1].x * ee[1].y);
    float tp  = scan_mul_incl(lp);
    float tin = DPPF(1.0f, tp, WAVE_SHR1, 0xf, false);

    v2f om0 = 1.0f - ee[0], om1 = 1.0f - ee[1];
    float c1 = ee[0].x, c2 = c1 * ee[0].y, c3 = c2 * ee[1].x;
    v2f t01; t01.x = tin;      t01.y = tin * c1;
    v2f t23; t23.x = tin * c2; t23.y = tin * c3;
    v2f w01 = om0 * t01, w23 = om1 * t23;

    // reweight (scale 0.5 uniform -> cancels in normalization)
    float wprev = DPPF(0.0f, w23.y, WAVE_SHR1, 0xf, false);  // lane-1's w3; lane0 -> 0
    float wnext = DPPF(0.0f, w01.x, WAVE_SHL1, 0xf, false);  // lane+1's w0; lane63 -> 0
    float m0 = fmaxf(wprev, w01.x), m1 = fmaxf(w01.x, w01.y),
          m2 = fmaxf(w01.y, w23.x), m3 = fmaxf(w23.x, w23.y),
          m4 = fmaxf(w23.y, wnext);
    float wr0 = 0.5f * (m0 + m1) + CADD, wr1 = 0.5f * (m1 + m2) + CADD,
          wr2 = 0.5f * (m2 + m3) + CADD, wr3 = 0.5f * (m3 + m4) + CADD;

    // CDF: lane-local inclusive sums + wave add-scan
    float s0 = wr0, s1 = s0 + wr1, s2 = s1 + wr2, s3 = s2 + wr3;
    float incl = scan_add_incl(s3);
    float exb  = DPPF(0.0f, incl, WAVE_SHR1, 0xf, true);
    float invT = frcp(readlanef(incl, 63));
    v2f cdfa; cdfa.x = (exb + s0) * invT; cdfa.y = (exb + s1) * invT;
    v2f cdfb; cdfb.x = (exb + s2) * invT; cdfb.y = (exb + s3) * invT;
    *(v2f*)&cdf_s[wid][(lane << 2) + 0] = cdfa;
    *(v2f*)&cdf_s[wid][(lane << 2) + 2] = cdfb;
    const float* cdf = cdf_s[wid];
    // no __syncthreads(): LDS row is wave-private; compiler orders via lgkmcnt

    // Level-1 pivots are wave-uniform register values: cdf[63]/[127]/[191]
    // live in lanes 15/31/47's cdfb.y. Bit-identical to the LDS copy.
    const float p63  = readlanef(cdfb.y, 15);
    const float p127 = readlanef(cdfb.y, 31);
    const float p191 = readlanef(cdfb.y, 47);

    // -------- inverse-CDF sampling: reg level + 2 LDS levels + final b128 --------
    // (R6 structure: LDS levels issue on the LDS pipe and are latency-hidden by
    // TLP; register-select variants ADD VALU issue slots -> measured regression R7)
    // Invariant at each level: answer inds in [base, base+S) and cdf[base+S-1] > u.
    // Bin selection bit-identical to np.searchsorted(cdf, u, 'right').
    float zlf[2], zvs[2];
    float ubase = (float)lane * 0.015625f;   // u = lane*2^-6 + (jj+0.5)*2^-7, exact
#pragma unroll
    for (int jj = 0; jj < 2; jj++) {
        float u = ubase + (jj ? 0.01171875f : 0.00390625f);
        int base = (((int)(p63 <= u) + (int)(p127 <= u) + (int)(p191 <= u)) << 6);
        {   // level 2: stride 16
            float qa = cdf[base + 15], qb = cdf[base + 31], qc = cdf[base + 47];
            base += (((int)(qa <= u) + (int)(qb <= u) + (int)(qc <= u)) << 4);
        }
        {   // level 3: stride 4
            float ra_ = cdf[base + 3], rb_ = cdf[base + 7], rc_ = cdf[base + 11];
            base += (((int)(ra_ <= u) + (int)(rb_ <= u) + (int)(rc_ <= u)) << 2);
        }
        v4f r = *(const v4f*)(cdf + base);          // ds_read_b128, 16B-aligned
        int bm1 = base - 1; if (bm1 < 0) bm1 = 0;
        float cm1 = cdf[bm1];                        // cdf[max(base-1,0)] == np's fallback
        bool le0 = (r.x <= u), le1 = (r.y <= u), le2 = (r.z <= u);  // r.w > u by invariant
        int cnt  = (int)le0 + (int)le1 + (int)le2;
        int inds = base + cnt;
        float c1v = le2 ? r.w : (le1 ? r.z : (le0 ? r.y : r.x));    // cdf[inds]
        float c0  = le2 ? r.z : (le1 ? r.y : (le0 ? r.x : cm1));    // cdf[max(inds-1,0)]
        float dnm = c1v - c0;
        dnm = (dnm < 1e-8f) ? 1.0f : dnm;
        float t = (u - c0) * frcp(dnm);
        t = t < 0.0f ? 0.0f : (t > 1.0f ? 1.0f : t);
        // inds>=1: b0=-1+(inds-1)*DLT, b1-b0=DLT exactly; inds==0: zlf=-1
        float f = (inds == 0) ? 0.0f : ((float)(inds - 1) + t);
        zlf[jj] = fmaf(DLT, f, -1.0f);
        zvs[jj] = f * 0.00390625f;   // (zlf+1)/2 to <=1ulp: exact 2^-8 * f
    }

    // ---------------- fine render (one packed pair per lane) ----------------
    float zlf2 = DPPF(zlf[1], zlf[0], WAVE_SHL1, 0xf, false);  // zlf[2*lane+2]; lane63 -> own zlf[1] => del.y = 0
    v2f del; del.x = zlf[1] - zlf[0]; del.y = zlf2 - zlf[1];
    v2f zf;  zf.x = fexp2(zlf[0] * L2_10); zf.y = fexp2(zlf[1] * L2_10);
    v2f invz; invz.x = frcp(zf.x); invz.y = frcp(zf.y);
    v2f px = dx * zf + ox, py = dy * zf + oy, pz = dz * zf + oz;
    v2f nsq = px * px + py * py + pz * pz;
    v2f rn; rn.x = frsq(nsq.x); rn.y = frsq(nsq.y);
    v2f t2 = 2.0f - rn;
    v2f fs = t2 * t2;
    v2f fc = rn * t2;
    v2f ssq, fac;
    ssq.x = nsq.x > 1.0f ? fs.x : nsq.x;  fac.x = nsq.x > 1.0f ? fc.x : 1.0f;
    ssq.y = nsq.y > 1.0f ? fs.y : nsq.y;  fac.y = nsq.y > 1.0f ? fc.y : 1.0f;
    v2f sr = C2 * ssq;
    v2f sg; sg.x = fexp2(sr.x); sg.y = fexp2(sr.y);        // exp(-4*ssq)
    v2f ea = (C25 * sg) * del;                             // log2(ef)  (lane63: ea.y = 0 exactly)
    v2f ef; ef.x = fexp2(ea.x); ef.y = fexp2(ea.y);        // exp(-sig*del)

    v2f sx = px * fac, sy = py * fac, sz = pz * fac;       // contracted point
    v2f axr = sx * (-L2_E) + dxn;                          // pk_mul + pk_fma per channel
    v2f axg = sy * (-L2_E) + dyn;
    v2f axb = sz * (-L2_E) + dzn;
    v2f er; er.x = fexp2(axr.x); er.y = fexp2(axr.y);
    v2f eg; eg.x = fexp2(axg.x); eg.y = fexp2(axg.y);
    v2f eb; eb.x = fexp2(axb.x); eb.y = fexp2(axb.y);
    v2f dr = 1.0f + er, dg = 1.0f + eg, db = 1.0f + eb;
    v2f rv; rv.x = frcp(dr.x); rv.y = frcp(dr.y);
    v2f gv; gv.x = frcp(dg.x); gv.y = frcp(dg.y);
    v2f bv; bv.x = frcp(db.x); bv.y = frcp(db.y);

    // log-domain transmittance: fused add-scan on log2(ef) + one exp2
    float asum = ea.x + ea.y;
    float tincl = scan_add_incl(asum);                       // inclusive log-sum
    float texc  = DPPF(0.0f, tincl, WAVE_SHR1, 0xf, true);   // exclusive; lane0 -> 0
    float tinf  = fexp2(texc);                               // incoming transmittance
    float Ttot  = fexp2(readlanef(tincl, 63));               // total transmittance = 1 - sum(wf)
    float wf0 = (1.0f - ef.x) * tinf;
    float wf1 = (1.0f - ef.y) * (tinf * ef.x);
    v2f wfv; wfv.x = wf0; wfv.y = wf1;

    v2f pr = wfv * rv, pg = wfv * gv, pb = wfv * bv, pi = wfv * invz;
    float ar = scan_add_incl(pr.x + pr.y);    // lane63 = total
    float ag = scan_add_incl(pg.x + pg.y);
    float ab = scan_add_incl(pb.x + pb.y);
    float ai = scan_add_incl(pi.x + pi.y);

    // ---------------- outputs: [image N*3][wf N*128][zvs N*128][invdepth N] ----------------
    // 32-bit offsets: total elements 65536*260 < 2^25
    const unsigned NN = (unsigned)N;
    float* wf_base  = out + 3u * NN;
    float* zvs_base = wf_base + NN * (unsigned)SF;
    float* inv_base = zvs_base + NN * (unsigned)SF;
    unsigned col = (unsigned)ray * (unsigned)SF + (unsigned)(lane << 1);
    *(float2*)(wf_base + col) = make_float2(wf0, wf1);
    *(float2*)(zvs_base + col) = make_float2(zvs[0], zvs[1]);
    if (lane == 63) {
        out[(unsigned)ray * 3u + 0u] = fmaf(Ttot, bgp[0], ar);
        out[(unsigned)ray * 3u + 1u] = fmaf(Ttot, bgp[1], ag);
        out[(unsigned)ray * 3u + 2u] = fmaf(Ttot, bgp[2], ab);
        inv_base[(unsigned)ray] = ai;
    }
}

extern "C" void kernel_launch(void* const* d_in, const int* in_sizes, int n_in,
                              void* d_out, int out_size, void* d_ws, size_t ws_size,
                              hipStream_t stream) {
    const float* rays_o = (const float*)d_in[0];
    const float* rays_d = (const float*)d_in[1];
    const float* bg     = (const float*)d_in[2];
    float* out = (float*)d_out;
    int N = in_sizes[0] / 3;
    int blocks = (N + WPB - 1) / WPB;
    nerf_render<<<blocks, BLOCK, 0, stream>>>(rays_o, rays_d, bg, out, N);
}